// Round 1
// baseline (1033.818 us; speedup 1.0000x reference)
//
#include <hip/hip_runtime.h>
#include <cstdint>
#include <cstddef>

// Problem constants (fixed shapes from the reference)
#define D_MODEL 2048
#define T_SEQ   2048
#define N_BATCH 4
#define N_HEAD  16
#define HD      128
#define M_ROWS  (N_BATCH * T_SEQ)   // 8192
#define N_QKV   (3 * D_MODEL)       // 6144

typedef short          s8x  __attribute__((ext_vector_type(8)));   // 8 x bf16 (4 VGPRs)
typedef float          f4x  __attribute__((ext_vector_type(4)));
typedef float          f4v  __attribute__((ext_vector_type(4)));
typedef unsigned short u16;
typedef u16            u16x8 __attribute__((ext_vector_type(8)));

// fp32 -> bf16, round-to-nearest-even
__device__ __forceinline__ u16 f2bf(float f) {
    union { float f; unsigned u; } v; v.f = f;
    unsigned r = (v.u + 0x7FFFu + ((v.u >> 16) & 1u)) >> 16;
    return (u16)r;
}

// async global->LDS, 16B per lane. LDS dest must be wave-uniform base; HW
// writes lane i at base + i*16. Global src is per-lane.
__device__ __forceinline__ void glds16(const void* g, void* l) {
    __builtin_amdgcn_global_load_lds(
        (const __attribute__((address_space(1))) void*)g,
        (__attribute__((address_space(3))) void*)l, 16, 0, 0);
}

// ---------------------------------------------------------------------------
// fp32 -> bf16 bulk convert (8 elements / thread / iter)
// ---------------------------------------------------------------------------
__global__ void cvt_f32_bf16(const float* __restrict__ in, u16* __restrict__ out, int n8) {
    int i = blockIdx.x * blockDim.x + threadIdx.x;
    int stride = gridDim.x * blockDim.x;
    for (; i < n8; i += stride) {
        f4v a = reinterpret_cast<const f4v*>(in)[2 * i];
        f4v b = reinterpret_cast<const f4v*>(in)[2 * i + 1];
        u16x8 o;
        o[0] = f2bf(a[0]); o[1] = f2bf(a[1]); o[2] = f2bf(a[2]); o[3] = f2bf(a[3]);
        o[4] = f2bf(b[0]); o[5] = f2bf(b[1]); o[6] = f2bf(b[2]); o[7] = f2bf(b[3]);
        reinterpret_cast<u16x8*>(out)[i] = o;
    }
}

// ---------------------------------------------------------------------------
// C[m][n] = sum_k A[m][k]*B[n][k] + bias[n]   (B^T layout, m97 structure)
// 128x128 tile, BK=32, 256 threads = 4 waves (2x2), 4x4 16x16 frags per wave.
// ---------------------------------------------------------------------------
template<bool OUT_BF16>
__global__ __launch_bounds__(256)
void gemm_bt(const u16* __restrict__ A, const u16* __restrict__ B,
             const float* __restrict__ bias, void* __restrict__ C,
             int M, int N, int K, int nbn) {
    __shared__ u16 As[128 * 32];
    __shared__ u16 Bs[128 * 32];

    int nwg = gridDim.x;
    int wg  = blockIdx.x;
    int qx  = nwg >> 3;                 // nwg % 8 == 0 by construction
    wg = (wg & 7) * qx + (wg >> 3);     // XCD-aware swizzle
    int bm = wg / nbn, bn = wg % nbn;

    int t   = threadIdx.x;
    int wid = t >> 6;
    int l15 = t & 15, l4 = (t >> 4) & 3;
    int wr  = wid >> 1, wc = wid & 1;

    f4x acc[4][4] = {};

    const u16* ga = A + (size_t)(bm * 128 + (t >> 2)) * K + (t & 3) * 8;
    const u16* gb = B + (size_t)(bn * 128 + (t >> 2)) * K + (t & 3) * 8;
    char* lA = (char*)As + wid * 1024;
    char* lB = (char*)Bs + wid * 1024;

    for (int k0 = 0; k0 < K; k0 += 32) {
        glds16(ga,              lA);
        glds16(ga + 64 * (size_t)K, lA + 4096);
        glds16(gb,              lB);
        glds16(gb + 64 * (size_t)K, lB + 4096);
        ga += 32; gb += 32;
        __syncthreads();

        s8x af[4], bfr[4];
        #pragma unroll
        for (int m = 0; m < 4; m++) {
            af[m]  = *reinterpret_cast<const s8x*>(As + (wr * 64 + m * 16 + l15) * 32 + l4 * 8);
            bfr[m] = *reinterpret_cast<const s8x*>(Bs + (wc * 64 + m * 16 + l15) * 32 + l4 * 8);
        }
        #pragma unroll
        for (int m = 0; m < 4; m++)
            #pragma unroll
            for (int n = 0; n < 4; n++)
                acc[m][n] = __builtin_amdgcn_mfma_f32_16x16x32_bf16(af[m], bfr[n], acc[m][n], 0, 0, 0);
        __syncthreads();
    }

    int row0 = bm * 128 + wr * 64;
    int col0 = bn * 128 + wc * 64;
    #pragma unroll
    for (int n = 0; n < 4; n++) {
        int col = col0 + n * 16 + l15;
        float bv = bias[col];
        #pragma unroll
        for (int m = 0; m < 4; m++) {
            #pragma unroll
            for (int r = 0; r < 4; r++) {
                int row = row0 + m * 16 + l4 * 4 + r;
                float v = acc[m][n][r] + bv;
                if (OUT_BF16) ((u16*)C)[(size_t)row * N + col]   = f2bf(v);
                else          ((float*)C)[(size_t)row * N + col] = v;
            }
        }
    }
}

// ---------------------------------------------------------------------------
// Flash attention. Grid = 64 (b*h) x 16 q-blocks. 256 threads = 4 waves.
// Q-tile 128 rows (32/wave, held in regs), KV-tile 64.
//  K staged via global_load_lds with slot-XOR swizzle (linear LDS dest,
//  pre-swizzled global source). V reg-transposed into padded Vt[128][72].
//  Online softmax in exp2 domain; P through per-wave padded LDS.
// ---------------------------------------------------------------------------
__global__ __launch_bounds__(256)
void attn(const u16* __restrict__ qkv, const int* __restrict__ mask,
          u16* __restrict__ att) {
    __shared__ u16  Ks[64 * 128];      // 16 KB, [row][slot] 16B slots, XOR-swizzled
    __shared__ u16  Vt[128 * 72];      // 18 KB, transposed V, padded rows
    __shared__ u16  Pl[4][32 * 72];    // 18 KB, per-wave P tile, padded rows
    __shared__ float mb[64];           // mask bias for current KV tile

    int wg = blockIdx.x;               // 1024
    int q8 = gridDim.x >> 3;
    wg = (wg & 7) * q8 + (wg >> 3);    // XCD swizzle: q-blocks of one head stay on one XCD
    int bh = wg >> 4;                  // b*16 + h
    int qb = wg & 15;
    int b  = bh >> 4, h = bh & 15;

    int t = threadIdx.x, wid = t >> 6;
    int lane = t & 63, l15 = lane & 15, l4 = lane >> 4;

    const size_t rs = N_QKV;           // 6144 qkv row stride
    const u16* qbase = qkv + (size_t)(b * T_SEQ) * rs;
    const u16* kbase = qbase + D_MODEL + h * HD;
    const u16* vbase = qbase + 2 * D_MODEL + h * HD;

    // Q fragments in registers: rows qb*128 + wid*32 + ms*16 + l15
    s8x qf[2][4];
    #pragma unroll
    for (int ms = 0; ms < 2; ms++)
        #pragma unroll
        for (int kk = 0; kk < 4; kk++) {
            int row = qb * 128 + wid * 32 + ms * 16 + l15;
            qf[ms][kk] = *reinterpret_cast<const s8x*>(
                qbase + (size_t)row * rs + h * HD + kk * 32 + l4 * 8);
        }

    f4x acc[2][8] = {};
    float mrun[2][4], lrun[2][4];
    #pragma unroll
    for (int ms = 0; ms < 2; ms++)
        #pragma unroll
        for (int r = 0; r < 4; r++) { mrun[ms][r] = -__builtin_inff(); lrun[ms][r] = 0.f; }

    const float cs = 0.08838834764831845f * 1.4426950408889634f; // 1/sqrt(128)*log2(e)

    int vp = t & 31;    // key pair index (k = 2vp, 2vp+1)
    int vs = t >> 5;    // d slot (d0 = vs*16)
    u16* Pw = Pl[wid];

    for (int kv0 = 0; kv0 < T_SEQ; kv0 += 64) {
        // --- stage K (4 wave-uniform-dest statements) ---
        {
            int krow = t >> 4, s = t & 15;
            #pragma unroll
            for (int i = 0; i < 4; i++) {
                int row = i * 16 + krow;
                const u16* src = kbase + (size_t)(kv0 + row) * rs + ((s ^ (row & 7)) * 8);
                glds16(src, (char*)Ks + i * 4096 + wid * 1024);
            }
        }
        // --- V tile -> regs ---
        s8x v0a = *reinterpret_cast<const s8x*>(vbase + (size_t)(kv0 + 2 * vp) * rs + vs * 16);
        s8x v0b = *reinterpret_cast<const s8x*>(vbase + (size_t)(kv0 + 2 * vp) * rs + vs * 16 + 8);
        s8x v1a = *reinterpret_cast<const s8x*>(vbase + (size_t)(kv0 + 2 * vp + 1) * rs + vs * 16);
        s8x v1b = *reinterpret_cast<const s8x*>(vbase + (size_t)(kv0 + 2 * vp + 1) * rs + vs * 16 + 8);
        // --- mask bias ---
        if (t < 64) mb[t] = mask[b * T_SEQ + kv0 + t] ? 0.f : -__builtin_inff();
        // --- transpose V into Vt (pairs packed as b32; conflict-free) ---
        #pragma unroll
        for (int j = 0; j < 8; j++) {
            unsigned w0 = (u16)v0a[j] | ((unsigned)(u16)v1a[j] << 16);
            *reinterpret_cast<unsigned*>(&Vt[(vs * 16 + j) * 72 + 2 * vp]) = w0;
            unsigned w1 = (u16)v0b[j] | ((unsigned)(u16)v1b[j] << 16);
            *reinterpret_cast<unsigned*>(&Vt[(vs * 16 + 8 + j) * 72 + 2 * vp]) = w1;
        }
        __syncthreads();

        // --- QK^T: S[q][k], 32 MFMA / wave ---
        f4x sf[2][4] = {};
        #pragma unroll
        for (int t4 = 0; t4 < 4; t4++) {
            s8x kf[4];
            #pragma unroll
            for (int kk = 0; kk < 4; kk++) {
                int row  = t4 * 16 + l15;
                int slot = (kk * 4 + l4) ^ (row & 7);
                kf[kk] = *reinterpret_cast<const s8x*>(Ks + row * 128 + slot * 8);
            }
            #pragma unroll
            for (int ms = 0; ms < 2; ms++)
                #pragma unroll
                for (int kk = 0; kk < 4; kk++)
                    sf[ms][t4] = __builtin_amdgcn_mfma_f32_16x16x32_bf16(qf[ms][kk], kf[kk], sf[ms][t4], 0, 0, 0);
        }

        // mask bias add (col = t4*16 + l15)
        float mbv[4];
        #pragma unroll
        for (int t4 = 0; t4 < 4; t4++) mbv[t4] = mb[t4 * 16 + l15];
        #pragma unroll
        for (int ms = 0; ms < 2; ms++)
            #pragma unroll
            for (int t4 = 0; t4 < 4; t4++)
                sf[ms][t4] += mbv[t4];

        // --- online softmax (base-2 domain, max over raw scores) ---
        #pragma unroll
        for (int ms = 0; ms < 2; ms++) {
            float mx[4];
            #pragma unroll
            for (int r = 0; r < 4; r++) {
                float a0 = fmaxf(fmaxf(sf[ms][0][r], sf[ms][1][r]),
                                 fmaxf(sf[ms][2][r], sf[ms][3][r]));
                #pragma unroll
                for (int sh = 1; sh <= 8; sh <<= 1) a0 = fmaxf(a0, __shfl_xor(a0, sh));
                mx[r] = a0;
            }
            f4x fv; float mc[4];
            #pragma unroll
            for (int r = 0; r < 4; r++) {
                float mn = fmaxf(mrun[ms][r], mx[r]);
                float f  = exp2f((mrun[ms][r] - mn) * cs);
                mrun[ms][r] = mn;
                lrun[ms][r] *= f;
                fv[r] = f;
                mc[r] = mn * cs;
            }
            #pragma unroll
            for (int dt = 0; dt < 8; dt++) acc[ms][dt] *= fv;
            #pragma unroll
            for (int t4 = 0; t4 < 4; t4++) {
                #pragma unroll
                for (int r = 0; r < 4; r++) {
                    float p = exp2f(sf[ms][t4][r] * cs - mc[r]);
                    lrun[ms][r] += p;
                    Pw[(ms * 16 + l4 * 4 + r) * 72 + t4 * 16 + l15] = f2bf(p);
                }
            }
        }
        asm volatile("" ::: "memory"); // order P writes vs s8x reads (same wave)

        // --- PV: acc += P * V, 32 MFMA / wave ---
        s8x pa[2][2];
        #pragma unroll
        for (int ms = 0; ms < 2; ms++)
            #pragma unroll
            for (int ks = 0; ks < 2; ks++)
                pa[ms][ks] = *reinterpret_cast<const s8x*>(Pw + (ms * 16 + l15) * 72 + ks * 32 + l4 * 8);
        #pragma unroll
        for (int dt = 0; dt < 8; dt++) {
            s8x vbf[2];
            #pragma unroll
            for (int ks = 0; ks < 2; ks++)
                vbf[ks] = *reinterpret_cast<const s8x*>(Vt + (dt * 16 + l15) * 72 + ks * 32 + l4 * 8);
            #pragma unroll
            for (int ms = 0; ms < 2; ms++)
                #pragma unroll
                for (int ks = 0; ks < 2; ks++)
                    acc[ms][dt] = __builtin_amdgcn_mfma_f32_16x16x32_bf16(pa[ms][ks], vbf[ks], acc[ms][dt], 0, 0, 0);
        }
        __syncthreads();
    }

    // --- epilogue: normalize and store bf16 attended ---
    #pragma unroll
    for (int ms = 0; ms < 2; ms++) {
        f4x inv;
        #pragma unroll
        for (int r = 0; r < 4; r++) {
            float s = lrun[ms][r];
            #pragma unroll
            for (int sh = 1; sh <= 8; sh <<= 1) s += __shfl_xor(s, sh);
            inv[r] = 1.f / s;
        }
        #pragma unroll
        for (int dt = 0; dt < 8; dt++) {
            f4x o = acc[ms][dt] * inv;
            #pragma unroll
            for (int r = 0; r < 4; r++) {
                int row = qb * 128 + wid * 32 + ms * 16 + l4 * 4 + r;
                int col = h * HD + dt * 16 + l15;
                att[(size_t)(b * T_SEQ + row) * D_MODEL + col] = f2bf(o[r]);
            }
        }
    }
}

// ---------------------------------------------------------------------------
// Launcher
// ---------------------------------------------------------------------------
extern "C" void kernel_launch(void* const* d_in, const int* in_sizes, int n_in,
                              void* d_out, int out_size, void* d_ws, size_t ws_size,
                              hipStream_t stream) {
    (void)in_sizes; (void)n_in; (void)out_size; (void)ws_size;

    const float* x    = (const float*)d_in[0];
    const int*   mask = (const int*)d_in[1];
    const float* Wq   = (const float*)d_in[2];
    const float* bq   = (const float*)d_in[3];
    const float* Wk   = (const float*)d_in[4];
    const float* bk   = (const float*)d_in[5];
    const float* Wv   = (const float*)d_in[6];
    const float* bv   = (const float*)d_in[7];
    const float* Wo   = (const float*)d_in[8];
    const float* bo   = (const float*)d_in[9];
    float* out = (float*)d_out;

    char* ws = (char*)d_ws;
    // workspace layout (bytes):
    u16*   xb   = (u16*)(ws);               // x bf16        8192x2048 : 33,554,432
    u16*   wqkv = (u16*)(ws + 33554432);    // Wq|Wk|Wv bf16 6144x2048 : 25,165,824
    u16*   wo   = (u16*)(ws + 58720256);    // Wo bf16       2048x2048 :  8,388,608
    float* bqkv = (float*)(ws + 67108864);  // bq|bk|bv fp32 6144      :     24,576
    u16*   qkvb = (u16*)(ws + 67133440);    // qkv bf16      8192x6144 :100,663,296
    u16*   attb = (u16*)(ws + 167796736);   // attended bf16 8192x2048 : 33,554,432
                                            // total: 201,351,168 B

    cvt_f32_bf16<<<2048, 256, 0, stream>>>(x,  xb,               16777216 / 8);
    cvt_f32_bf16<<<1024, 256, 0, stream>>>(Wq, wqkv,              4194304 / 8);
    cvt_f32_bf16<<<1024, 256, 0, stream>>>(Wk, wqkv + 4194304,    4194304 / 8);
    cvt_f32_bf16<<<1024, 256, 0, stream>>>(Wv, wqkv + 8388608,    4194304 / 8);
    cvt_f32_bf16<<<1024, 256, 0, stream>>>(Wo, wo,                4194304 / 8);
    hipMemcpyAsync(bqkv,        bq, 2048 * 4, hipMemcpyDeviceToDevice, stream);
    hipMemcpyAsync(bqkv + 2048, bk, 2048 * 4, hipMemcpyDeviceToDevice, stream);
    hipMemcpyAsync(bqkv + 4096, bv, 2048 * 4, hipMemcpyDeviceToDevice, stream);

    // QKV projection: C[8192][6144] = x * [Wq|Wk|Wv]^T + b
    gemm_bt<true><<<64 * 48, 256, 0, stream>>>(xb, wqkv, bqkv, qkvb, M_ROWS, N_QKV, D_MODEL, 48);
    // fused flash attention -> attended bf16 [8192][2048]
    attn<<<1024, 256, 0, stream>>>(qkvb, mask, attb);
    // output projection: out fp32 = attended * Wo^T + bo
    gemm_bt<false><<<64 * 16, 256, 0, stream>>>(attb, wo, bo, out, M_ROWS, D_MODEL, D_MODEL, 16);
}

// Round 2
// 880.867 us; speedup vs baseline: 1.1736x; 1.1736x over previous
//
#include <hip/hip_runtime.h>
#include <cstdint>
#include <cstddef>

// Problem constants (fixed shapes from the reference)
#define D_MODEL 2048
#define T_SEQ   2048
#define N_BATCH 4
#define N_HEAD  16
#define HD      128
#define M_ROWS  (N_BATCH * T_SEQ)   // 8192
#define N_QKV   (3 * D_MODEL)       // 6144

typedef short          s8x  __attribute__((ext_vector_type(8)));   // 8 x bf16 (4 VGPRs)
typedef float          f4x  __attribute__((ext_vector_type(4)));
typedef float          f4v  __attribute__((ext_vector_type(4)));
typedef unsigned short u16;
typedef u16            u16x8 __attribute__((ext_vector_type(8)));

// fp32 -> bf16, round-to-nearest-even
__device__ __forceinline__ u16 f2bf(float f) {
    union { float f; unsigned u; } v; v.f = f;
    unsigned r = (v.u + 0x7FFFu + ((v.u >> 16) & 1u)) >> 16;
    return (u16)r;
}

// async global->LDS, 16B per lane (GEMM staging only)
__device__ __forceinline__ void glds16(const void* g, void* l) {
    __builtin_amdgcn_global_load_lds(
        (const __attribute__((address_space(1))) void*)g,
        (__attribute__((address_space(3))) void*)l, 16, 0, 0);
}

// DPP row_ror butterfly step: lane i of each 16-lane row reads lane (i+N)&15
template<int CTRL>
__device__ __forceinline__ float dppror(float v) {
    int i = __builtin_bit_cast(int, v);
    int r = __builtin_amdgcn_update_dpp(i, i, CTRL, 0xf, 0xf, true);
    return __builtin_bit_cast(float, r);
}
// max over the 16 lanes of a DPP row, result broadcast to all 16
__device__ __forceinline__ float rowmax16(float v) {
    v = fmaxf(v, dppror<0x128>(v));   // row_ror:8
    v = fmaxf(v, dppror<0x124>(v));   // row_ror:4
    v = fmaxf(v, dppror<0x122>(v));   // row_ror:2
    v = fmaxf(v, dppror<0x121>(v));   // row_ror:1
    return v;
}

// ---------------------------------------------------------------------------
// fp32 -> bf16 bulk convert (8 elements / thread / iter)
// ---------------------------------------------------------------------------
__global__ void cvt_f32_bf16(const float* __restrict__ in, u16* __restrict__ out, int n8) {
    int i = blockIdx.x * blockDim.x + threadIdx.x;
    int stride = gridDim.x * blockDim.x;
    for (; i < n8; i += stride) {
        f4v a = reinterpret_cast<const f4v*>(in)[2 * i];
        f4v b = reinterpret_cast<const f4v*>(in)[2 * i + 1];
        u16x8 o;
        o[0] = f2bf(a[0]); o[1] = f2bf(a[1]); o[2] = f2bf(a[2]); o[3] = f2bf(a[3]);
        o[4] = f2bf(b[0]); o[5] = f2bf(b[1]); o[6] = f2bf(b[2]); o[7] = f2bf(b[3]);
        reinterpret_cast<u16x8*>(out)[i] = o;
    }
}

// ---------------------------------------------------------------------------
// C[m][n] = (sum_k A[m][k]*B[n][k] + bias[n]) * (col<qcols ? qscale : 1)
// (B^T layout, m97 structure) 128x128 tile, BK=32, 4 waves, 4x4 16x16 frags.
// ---------------------------------------------------------------------------
template<bool OUT_BF16>
__global__ __launch_bounds__(256)
void gemm_bt(const u16* __restrict__ A, const u16* __restrict__ B,
             const float* __restrict__ bias, void* __restrict__ C,
             int M, int N, int K, int nbn, float qscale, int qcols) {
    __shared__ u16 As[128 * 32];
    __shared__ u16 Bs[128 * 32];

    int nwg = gridDim.x;
    int wg  = blockIdx.x;
    int qx  = nwg >> 3;                 // nwg % 8 == 0 by construction
    wg = (wg & 7) * qx + (wg >> 3);     // XCD-aware swizzle
    int bm = wg / nbn, bn = wg % nbn;

    int t   = threadIdx.x;
    int wid = t >> 6;
    int l15 = t & 15, l4 = (t >> 4) & 3;
    int wr  = wid >> 1, wc = wid & 1;

    f4x acc[4][4] = {};

    const u16* ga = A + (size_t)(bm * 128 + (t >> 2)) * K + (t & 3) * 8;
    const u16* gb = B + (size_t)(bn * 128 + (t >> 2)) * K + (t & 3) * 8;
    char* lA = (char*)As + wid * 1024;
    char* lB = (char*)Bs + wid * 1024;

    for (int k0 = 0; k0 < K; k0 += 32) {
        glds16(ga,              lA);
        glds16(ga + 64 * (size_t)K, lA + 4096);
        glds16(gb,              lB);
        glds16(gb + 64 * (size_t)K, lB + 4096);
        ga += 32; gb += 32;
        __syncthreads();

        s8x af[4], bfr[4];
        #pragma unroll
        for (int m = 0; m < 4; m++) {
            af[m]  = *reinterpret_cast<const s8x*>(As + (wr * 64 + m * 16 + l15) * 32 + l4 * 8);
            bfr[m] = *reinterpret_cast<const s8x*>(Bs + (wc * 64 + m * 16 + l15) * 32 + l4 * 8);
        }
        #pragma unroll
        for (int m = 0; m < 4; m++)
            #pragma unroll
            for (int n = 0; n < 4; n++)
                acc[m][n] = __builtin_amdgcn_mfma_f32_16x16x32_bf16(af[m], bfr[n], acc[m][n], 0, 0, 0);
        __syncthreads();
    }

    int row0 = bm * 128 + wr * 64;
    int col0 = bn * 128 + wc * 64;
    #pragma unroll
    for (int n = 0; n < 4; n++) {
        int col = col0 + n * 16 + l15;
        float bv = bias[col];
        float sc = (col < qcols) ? qscale : 1.0f;
        #pragma unroll
        for (int m = 0; m < 4; m++) {
            #pragma unroll
            for (int r = 0; r < 4; r++) {
                int row = row0 + m * 16 + l4 * 4 + r;
                float v = (acc[m][n][r] + bv) * sc;
                if (OUT_BF16) ((u16*)C)[(size_t)row * N + col]   = f2bf(v);
                else          ((float*)C)[(size_t)row * N + col] = v;
            }
        }
    }
}

// ---------------------------------------------------------------------------
// Flash attention v2. Grid = 64 (b*h) x 16 q-blocks. 256 threads = 4 waves.
// Q-tile 128 rows (32/wave in regs), KV-tile 64.
//  - K fragments read DIRECTLY from global (L2-resident; no LDS staging)
//  - V issued-early each tile (T14), reg-transposed into double-buffered Vt
//  - ONE __syncthreads per tile (loads already drained by then)
//  - softmax max-reduce via DPP row_ror butterfly (VALU pipe, no ds_bpermute)
//  - Q arrives pre-scaled by 1/sqrt(128)*log2(e)  (folded into GEMM1 epilogue)
// ---------------------------------------------------------------------------
__global__ __launch_bounds__(256, 2)
void attn(const u16* __restrict__ qkv, const int* __restrict__ mask,
          u16* __restrict__ att) {
    __shared__ u16  Vt[2][128 * 72];   // 2 x 18 KB, transposed V, padded rows
    __shared__ u16  Pl[4][32 * 72];    // 18 KB, per-wave P tile, padded rows
    __shared__ float mbuf[2][64];      // mask bias, double-buffered

    int wg = blockIdx.x;               // 1024
    int q8 = gridDim.x >> 3;
    wg = (wg & 7) * q8 + (wg >> 3);    // XCD swizzle: q-blocks of one head stay on one XCD
    int bh = wg >> 4;                  // b*16 + h
    int qb = wg & 15;
    int b  = bh >> 4, h = bh & 15;

    int t = threadIdx.x, wid = t >> 6;
    int lane = t & 63, l15 = lane & 15, l4 = lane >> 4;

    const size_t rs = N_QKV;           // 6144 qkv row stride
    const u16* qbase = qkv + (size_t)(b * T_SEQ) * rs;
    const u16* kbase = qbase + D_MODEL + h * HD;
    const u16* vbase = qbase + 2 * D_MODEL + h * HD;

    // Q fragments in registers (pre-scaled): rows qb*128 + wid*32 + ms*16 + l15
    s8x qf[2][4];
    #pragma unroll
    for (int ms = 0; ms < 2; ms++)
        #pragma unroll
        for (int kk = 0; kk < 4; kk++) {
            int row = qb * 128 + wid * 32 + ms * 16 + l15;
            qf[ms][kk] = *reinterpret_cast<const s8x*>(
                qbase + (size_t)row * rs + h * HD + kk * 32 + l4 * 8);
        }

    f4x acc[2][8] = {};
    float mrun[2][4], lrun[2][4];
    #pragma unroll
    for (int ms = 0; ms < 2; ms++)
        #pragma unroll
        for (int r = 0; r < 4; r++) { mrun[ms][r] = -__builtin_inff(); lrun[ms][r] = 0.f; }

    int vp = t & 31;    // key pair index (k = 2vp, 2vp+1)
    int vs = t >> 5;    // d slot (d0 = vs*16)
    u16* Pw = Pl[wid];

    // ---- prologue: V(0) -> Vt[0], mb(0) ----
    {
        s8x v0a = *reinterpret_cast<const s8x*>(vbase + (size_t)(2 * vp) * rs + vs * 16);
        s8x v0b = *reinterpret_cast<const s8x*>(vbase + (size_t)(2 * vp) * rs + vs * 16 + 8);
        s8x v1a = *reinterpret_cast<const s8x*>(vbase + (size_t)(2 * vp + 1) * rs + vs * 16);
        s8x v1b = *reinterpret_cast<const s8x*>(vbase + (size_t)(2 * vp + 1) * rs + vs * 16 + 8);
        if (t < 64) mbuf[0][t] = mask[b * T_SEQ + t] ? 0.f : -__builtin_inff();
        #pragma unroll
        for (int j = 0; j < 8; j++) {
            unsigned w0 = (u16)v0a[j] | ((unsigned)(u16)v1a[j] << 16);
            *reinterpret_cast<unsigned*>(&Vt[0][(vs * 16 + j) * 72 + 2 * vp]) = w0;
            unsigned w1 = (u16)v0b[j] | ((unsigned)(u16)v1b[j] << 16);
            *reinterpret_cast<unsigned*>(&Vt[0][(vs * 16 + 8 + j) * 72 + 2 * vp]) = w1;
        }
        __syncthreads();
    }

    for (int tt = 0; tt < T_SEQ / 64; tt++) {
        int kv0 = tt * 64;
        int cur = tt & 1, nxt = cur ^ 1;
        int kvn = kv0 + 64; if (kvn >= T_SEQ) kvn = 0;   // wrap: harmless dummy prefetch

        // --- issue V(t+1) loads EARLY (latency hides under QK+softmax+PV) ---
        s8x v0a = *reinterpret_cast<const s8x*>(vbase + (size_t)(kvn + 2 * vp) * rs + vs * 16);
        s8x v0b = *reinterpret_cast<const s8x*>(vbase + (size_t)(kvn + 2 * vp) * rs + vs * 16 + 8);
        s8x v1a = *reinterpret_cast<const s8x*>(vbase + (size_t)(kvn + 2 * vp + 1) * rs + vs * 16);
        s8x v1b = *reinterpret_cast<const s8x*>(vbase + (size_t)(kvn + 2 * vp + 1) * rs + vs * 16 + 8);

        // --- QK^T: S[q][k] (pre-scaled domain), K frags straight from global ---
        f4x sf[2][4] = {};
        #pragma unroll
        for (int t4 = 0; t4 < 4; t4++) {
            s8x kf[4];
            #pragma unroll
            for (int kk = 0; kk < 4; kk++)
                kf[kk] = *reinterpret_cast<const s8x*>(
                    kbase + (size_t)(kv0 + t4 * 16 + l15) * rs + kk * 32 + l4 * 8);
            #pragma unroll
            for (int ms = 0; ms < 2; ms++)
                #pragma unroll
                for (int kk = 0; kk < 4; kk++)
                    sf[ms][t4] = __builtin_amdgcn_mfma_f32_16x16x32_bf16(qf[ms][kk], kf[kk], sf[ms][t4], 0, 0, 0);
        }

        // mask bias add (col = t4*16 + l15)
        float mbv[4];
        #pragma unroll
        for (int t4 = 0; t4 < 4; t4++) mbv[t4] = mbuf[cur][t4 * 16 + l15];
        #pragma unroll
        for (int ms = 0; ms < 2; ms++)
            #pragma unroll
            for (int t4 = 0; t4 < 4; t4++)
                sf[ms][t4] += mbv[t4];

        // --- online softmax (exp2 domain; DPP row-max) ---
        #pragma unroll
        for (int ms = 0; ms < 2; ms++) {
            float mx[4];
            #pragma unroll
            for (int r = 0; r < 4; r++) {
                float a0 = fmaxf(fmaxf(sf[ms][0][r], sf[ms][1][r]),
                                 fmaxf(sf[ms][2][r], sf[ms][3][r]));
                mx[r] = rowmax16(a0);
            }
            f4x fv; float mc[4];
            #pragma unroll
            for (int r = 0; r < 4; r++) {
                float mn = fmaxf(mrun[ms][r], mx[r]);
                float f  = exp2f(mrun[ms][r] - mn);
                mrun[ms][r] = mn;
                lrun[ms][r] *= f;
                fv[r] = f;
                mc[r] = mn;
            }
            #pragma unroll
            for (int dt = 0; dt < 8; dt++) acc[ms][dt] *= fv;
            #pragma unroll
            for (int t4 = 0; t4 < 4; t4++) {
                #pragma unroll
                for (int r = 0; r < 4; r++) {
                    float p = exp2f(sf[ms][t4][r] - mc[r]);
                    lrun[ms][r] += p;
                    Pw[(ms * 16 + l4 * 4 + r) * 72 + t4 * 16 + l15] = f2bf(p);
                }
            }
        }
        asm volatile("" ::: "memory"); // order P writes vs s8x reads (same wave)

        // --- PV: acc += P * V(t), from Vt[cur] ---
        s8x pa[2][2];
        #pragma unroll
        for (int ms = 0; ms < 2; ms++)
            #pragma unroll
            for (int ks = 0; ks < 2; ks++)
                pa[ms][ks] = *reinterpret_cast<const s8x*>(Pw + (ms * 16 + l15) * 72 + ks * 32 + l4 * 8);
        #pragma unroll
        for (int dt = 0; dt < 8; dt++) {
            s8x vbf[2];
            #pragma unroll
            for (int ks = 0; ks < 2; ks++)
                vbf[ks] = *reinterpret_cast<const s8x*>(&Vt[cur][(dt * 16 + l15) * 72 + ks * 32 + l4 * 8]);
            #pragma unroll
            for (int ms = 0; ms < 2; ms++)
                #pragma unroll
                for (int ks = 0; ks < 2; ks++)
                    acc[ms][dt] = __builtin_amdgcn_mfma_f32_16x16x32_bf16(pa[ms][ks], vbf[ks], acc[ms][dt], 0, 0, 0);
        }

        // --- V(t+1) -> Vt[nxt], mb(t+1); Vt[nxt] not read by anyone this tile ---
        if (t < 64) mbuf[nxt][t] = mask[b * T_SEQ + kvn + t] ? 0.f : -__builtin_inff();
        #pragma unroll
        for (int j = 0; j < 8; j++) {
            unsigned w0 = (u16)v0a[j] | ((unsigned)(u16)v1a[j] << 16);
            *reinterpret_cast<unsigned*>(&Vt[nxt][(vs * 16 + j) * 72 + 2 * vp]) = w0;
            unsigned w1 = (u16)v0b[j] | ((unsigned)(u16)v1b[j] << 16);
            *reinterpret_cast<unsigned*>(&Vt[nxt][(vs * 16 + 8 + j) * 72 + 2 * vp]) = w1;
        }
        __syncthreads();   // single barrier per tile
    }

    // --- epilogue: normalize and store bf16 attended ---
    #pragma unroll
    for (int ms = 0; ms < 2; ms++) {
        f4x inv;
        #pragma unroll
        for (int r = 0; r < 4; r++) {
            float s = lrun[ms][r];
            #pragma unroll
            for (int sh = 1; sh <= 8; sh <<= 1) s += __shfl_xor(s, sh);
            inv[r] = 1.f / s;
        }
        #pragma unroll
        for (int dt = 0; dt < 8; dt++) {
            f4x o = acc[ms][dt] * inv;
            #pragma unroll
            for (int r = 0; r < 4; r++) {
                int row = qb * 128 + wid * 32 + ms * 16 + l4 * 4 + r;
                int col = h * HD + dt * 16 + l15;
                att[(size_t)(b * T_SEQ + row) * D_MODEL + col] = f2bf(o[r]);
            }
        }
    }
}

// ---------------------------------------------------------------------------
// Launcher
// ---------------------------------------------------------------------------
extern "C" void kernel_launch(void* const* d_in, const int* in_sizes, int n_in,
                              void* d_out, int out_size, void* d_ws, size_t ws_size,
                              hipStream_t stream) {
    (void)in_sizes; (void)n_in; (void)out_size; (void)ws_size;

    const float* x    = (const float*)d_in[0];
    const int*   mask = (const int*)d_in[1];
    const float* Wq   = (const float*)d_in[2];
    const float* bq   = (const float*)d_in[3];
    const float* Wk   = (const float*)d_in[4];
    const float* bk   = (const float*)d_in[5];
    const float* Wv   = (const float*)d_in[6];
    const float* bv   = (const float*)d_in[7];
    const float* Wo   = (const float*)d_in[8];
    const float* bo   = (const float*)d_in[9];
    float* out = (float*)d_out;

    char* ws = (char*)d_ws;
    // workspace layout (bytes):
    u16*   xb   = (u16*)(ws);               // x bf16        8192x2048 : 33,554,432
    u16*   wqkv = (u16*)(ws + 33554432);    // Wq|Wk|Wv bf16 6144x2048 : 25,165,824
    u16*   wo   = (u16*)(ws + 58720256);    // Wo bf16       2048x2048 :  8,388,608
    float* bqkv = (float*)(ws + 67108864);  // bq|bk|bv fp32 6144      :     24,576
    u16*   qkvb = (u16*)(ws + 67133440);    // qkv bf16      8192x6144 :100,663,296
    u16*   attb = (u16*)(ws + 167796736);   // attended bf16 8192x2048 : 33,554,432
                                            // total: 201,351,168 B

    cvt_f32_bf16<<<2048, 256, 0, stream>>>(x,  xb,               16777216 / 8);
    cvt_f32_bf16<<<1024, 256, 0, stream>>>(Wq, wqkv,              4194304 / 8);
    cvt_f32_bf16<<<1024, 256, 0, stream>>>(Wk, wqkv + 4194304,    4194304 / 8);
    cvt_f32_bf16<<<1024, 256, 0, stream>>>(Wv, wqkv + 8388608,    4194304 / 8);
    cvt_f32_bf16<<<1024, 256, 0, stream>>>(Wo, wo,                4194304 / 8);
    hipMemcpyAsync(bqkv,        bq, 2048 * 4, hipMemcpyDeviceToDevice, stream);
    hipMemcpyAsync(bqkv + 2048, bk, 2048 * 4, hipMemcpyDeviceToDevice, stream);
    hipMemcpyAsync(bqkv + 4096, bv, 2048 * 4, hipMemcpyDeviceToDevice, stream);

    const float cs = 0.08838834764831845f * 1.4426950408889634f; // 1/sqrt(128)*log2(e)

    // QKV projection: C[8192][6144] = x * [Wq|Wk|Wv]^T + b   (Q cols pre-scaled by cs)
    gemm_bt<true><<<64 * 48, 256, 0, stream>>>(xb, wqkv, bqkv, qkvb, M_ROWS, N_QKV, D_MODEL, 48, cs, D_MODEL);
    // fused flash attention -> attended bf16 [8192][2048]
    attn<<<1024, 256, 0, stream>>>(qkvb, mask, attb);
    // output projection: out fp32 = attended * Wo^T + bo
    gemm_bt<false><<<64 * 16, 256, 0, stream>>>(attb, wo, bo, out, M_ROWS, D_MODEL, D_MODEL, 16, 1.0f, 0);
}